// Round 6
// baseline (488.091 us; speedup 1.0000x reference)
//
#include <hip/hip_runtime.h>
#include <hip/hip_fp16.h>
#include <math.h>

// SelfAttentionModel B=4,S=4096,H=1,E=256. fp32 in/out (harness ABI), fp16 compute.
// Factored: scores = Xq*(Wq^T Wk/16)*Xk^T ; out = (P*Xv)*(Wo Wv)^T + bo.
// ws: Wmt(128KB) + Wov(128KB) + Kh fp16 [B][S][E] (8MB) + Vt fp16 [B][E][S] (8MB).
// attn: grid 512 (2 blocks/CU), block = 4 waves = 2 row-groups x 2 kv-halves
// over 32 q-rows; flash merge of halves in LDS; fused out-proj epilogue.

typedef __attribute__((ext_vector_type(8))) short short8;   // 8 fp16 = MFMA A/B frag
typedef __attribute__((ext_vector_type(4))) float floatx4;  // MFMA C/D frag
typedef __attribute__((ext_vector_type(4))) float float4v;

#define LOG2E 1.4426950408889634f

__device__ __forceinline__ short f2h(float f) {
    union { __half h; short s; } u; u.h = __float2half(f); return u.s;
}

__device__ __forceinline__ float row16_max(float v) {
    v = fmaxf(v, __shfl_xor(v, 1));
    v = fmaxf(v, __shfl_xor(v, 2));
    v = fmaxf(v, __shfl_xor(v, 4));
    v = fmaxf(v, __shfl_xor(v, 8));
    return v;
}
__device__ __forceinline__ float row16_sum(float v) {
    v += __shfl_xor(v, 1);
    v += __shfl_xor(v, 2);
    v += __shfl_xor(v, 4);
    v += __shfl_xor(v, 8);
    return v;
}

// ---------------------------------------------------------------------------
// Fused pre-pass (one launch):
//  blk [0,256):    Wmt[a][b] = sum_f Wk[f][a]*Wq[f][b] / 16     (M^T)
//  blk [256,512):  Wov[f][e] = sum_j Wo[f][j]*Wv[j][e]
//  blk [512,4608): Kh = fp16(Xk), same layout
//  blk [4608,5632): Vt = fp16(Xv) transposed to [B][E][S] (64x64 LDS tiles)
// ---------------------------------------------------------------------------
__global__ __launch_bounds__(256) void pre_kernel(
    const float* __restrict__ Wq, const float* __restrict__ Wk,
    const float* __restrict__ Wv, const float* __restrict__ Wo,
    const float* __restrict__ Xk, const float* __restrict__ Xv,
    short* __restrict__ Wmt, short* __restrict__ Wov,
    short* __restrict__ Kh, short* __restrict__ Vt)
{
    __shared__ short T[64 * 72];
    const int tid = threadIdx.x;
    const int blk = blockIdx.x;
    if (blk < 512) {
        float acc = 0.f;
        if (blk < 256) {
            const int a = blk;
            #pragma unroll 4
            for (int f = 0; f < 256; ++f)
                acc += Wk[f * 256 + a] * Wq[f * 256 + tid];
            Wmt[a * 256 + tid] = f2h(acc * 0.0625f);
        } else {
            const int f = blk - 256;
            #pragma unroll 4
            for (int j = 0; j < 256; ++j)
                acc += Wo[f * 256 + j] * Wv[j * 256 + tid];
            Wov[f * 256 + tid] = f2h(acc);
        }
    } else if (blk < 4608) {
        const long i = ((long)(blk - 512) * 256 + tid) * 4;
        float4v v = *(const float4v*)(Xk + i);
        union { short4 s4; short s[4]; } h;
        h.s[0] = f2h(v[0]); h.s[1] = f2h(v[1]); h.s[2] = f2h(v[2]); h.s[3] = f2h(v[3]);
        *(short4*)(Kh + i) = h.s4;
    } else {
        const int vb = blk - 4608;             // [0,1024)
        const int te = vb & 3, ts = (vb >> 2) & 63, b = vb >> 8;
        const int s0 = ts * 64, e0 = te * 64;
        #pragma unroll
        for (int i = 0; i < 4; ++i) {
            int idx = tid + i * 256;           // [0,1024)
            int sl = idx >> 4, f4 = idx & 15;
            float4v v = *(const float4v*)(Xv + ((long)(b * 4096 + s0 + sl) * 256 + e0 + f4 * 4));
            #pragma unroll
            for (int j = 0; j < 4; ++j)
                T[(f4 * 4 + j) * 72 + sl] = f2h(v[j]);
        }
        __syncthreads();
        #pragma unroll
        for (int i = 0; i < 2; ++i) {
            int idx = tid + i * 256;           // [0,512)
            int el = idx >> 3, s8 = idx & 7;
            *(short8*)(Vt + ((long)(b * 256 + e0 + el) * 4096 + s0 + s8 * 8)) =
                *(const short8*)(&T[el * 72 + s8 * 8]);
        }
    }
}

// ---------------------------------------------------------------------------
// attn: grid 512 = B(4) x qt(128) via xcd swizzle; block 256 = 4 waves:
// wave w: row-group rg=w>>1 (16 rows each), kv-half hf=w&1 (2048 keys each).
// Per-iter: stage 2 K-tiles [32][264] -> scores (16 MFMA) -> softmax ->
// P->LDS->A-frags -> PV (16 MFMA, V^T B-frags straight from global).
// End: flash-merge halves in LDS, hf0 waves run fused out-proj.
// ---------------------------------------------------------------------------
__global__ __launch_bounds__(256, 2) void attn_kernel(
    const float* __restrict__ Xq, const short* __restrict__ Kh,
    const short* __restrict__ Vt, const short* __restrict__ Wmt,
    const short* __restrict__ Wov, const float* __restrict__ bo,
    float* __restrict__ out)
{
    __shared__ short smem[19968];              // 39 KB
    // loop phase:   Kl half h at h*8448 ([32][264]); Pl at 16896 + w*640 ([16][40])
    // prologue:     QA = smem, per-wave [16][264] at w*4224
    // epilogue:     OX fp32 = (float*)smem (2 x [16][256]); OA = smem (2 x [16][264])
    float* ML = (float*)(smem + 19456);        // [4 waves][16 rows][2] (m,l)

    const int tid = threadIdx.x;
    const int w = tid >> 6, lane = tid & 63, c = lane & 15, q = lane >> 4;
    const int rg = w >> 1, hf = w & 1;
    const int x = blockIdx.x;
    const int xcd = x & 7;
    const int b = xcd >> 1;
    const int qt = ((x >> 3) << 1) | (xcd & 1);      // [0,128)
    const int wrow = b * 4096 + qt * 32 + rg * 16;   // this wave's 16 q-rows

    // ---- prologue: Q' = Xq * Wmt^T for own 16 rows (dup across hf waves) ----
    short8 xa[8];
    {
        const float* xq = Xq + (long)(wrow + c) * 256;
        #pragma unroll
        for (int kb = 0; kb < 8; ++kb) {
            const float* p = xq + kb * 32 + q * 8;
            float4v lo = *(const float4v*)(p);
            float4v hi = *(const float4v*)(p + 4);
            short8 t;
            t[0] = f2h(lo[0]); t[1] = f2h(lo[1]); t[2] = f2h(lo[2]); t[3] = f2h(lo[3]);
            t[4] = f2h(hi[0]); t[5] = f2h(hi[1]); t[6] = f2h(hi[2]); t[7] = f2h(hi[3]);
            xa[kb] = t;
        }
    }
    floatx4 qa[16];
    #pragma unroll
    for (int f = 0; f < 16; ++f) qa[f] = (floatx4){0.f, 0.f, 0.f, 0.f};
    #pragma unroll
    for (int kb = 0; kb < 8; ++kb)
        #pragma unroll
        for (int f = 0; f < 16; ++f) {
            short8 wf = *(const short8*)(Wmt + (f * 16 + c) * 256 + kb * 32 + q * 8);
            qa[f] = __builtin_amdgcn_mfma_f32_16x16x32_f16(xa[kb], wf, qa[f], 0, 0, 0);
        }
    #pragma unroll
    for (int f = 0; f < 16; ++f)
        #pragma unroll
        for (int r = 0; r < 4; ++r)
            smem[w * 4224 + (q * 4 + r) * 264 + f * 16 + c] = f2h(qa[f][r]);
    short8 qf[8];
    #pragma unroll
    for (int kb = 0; kb < 8; ++kb)
        qf[kb] = *(const short8*)(&smem[w * 4224 + c * 264 + kb * 32 + q * 8]);
    __syncthreads();

    floatx4 oacc[16];
    #pragma unroll
    for (int ef = 0; ef < 16; ++ef) oacc[ef] = (floatx4){0.f, 0.f, 0.f, 0.f};
    float mrow[4], lrow[4];
    #pragma unroll
    for (int r = 0; r < 4; ++r) { mrow[r] = -1e30f; lrow[r] = 0.f; }

    const short* khb = Kh + (long)b * 4096 * 256;
    const short* vtb = Vt + (long)b * 256 * 4096 + hf * 2048 + q * 8 + (long)c * 4096;
    short* Pw = smem + 16896 + w * 640;

    // prefetch K tiles for t=0 (both halves; each thread 8 short8 units)
    short8 kreg[8];
    #pragma unroll
    for (int i = 0; i < 8; ++i) {
        int u = tid + i * 256;
        int tile = u >> 10, row = (u >> 5) & 31, col = u & 31;
        kreg[i] = *(const short8*)(khb + (long)(tile * 2048 + row) * 256 + col * 8);
    }

    for (int t = 0; t < 64; ++t) {
        #pragma unroll
        for (int i = 0; i < 8; ++i) {
            int u = tid + i * 256;
            int tile = u >> 10, row = (u >> 5) & 31, col = u & 31;
            *(short8*)(&smem[tile * 8448 + row * 264 + col * 8]) = kreg[i];
        }
        __syncthreads();  // (A) K tiles staged

        // V^T B-frags straight from global (L1/L2-hot), issued early
        short8 vf[16];
        {
            const short* vp = vtb + t * 32;
            #pragma unroll
            for (int ef = 0; ef < 16; ++ef)
                vf[ef] = *(const short8*)(vp + (long)ef * 16 * 4096);
        }
        // prefetch next K tiles
        if (t + 1 < 64) {
            #pragma unroll
            for (int i = 0; i < 8; ++i) {
                int u = tid + i * 256;
                int tile = u >> 10, row = (u >> 5) & 31, col = u & 31;
                kreg[i] = *(const short8*)(khb + (long)(tile * 2048 + (t + 1) * 32 + row) * 256 + col * 8);
            }
        }

        // scores = Q' * K_tile^T  (own half's tile)
        const short* Klh = smem + hf * 8448;
        floatx4 s0f = (floatx4){0.f, 0.f, 0.f, 0.f};
        floatx4 s1f = (floatx4){0.f, 0.f, 0.f, 0.f};
        #pragma unroll
        for (int kb = 0; kb < 8; ++kb) {
            short8 k0 = *(const short8*)(&Klh[c * 264 + (kb * 4 + q) * 8]);
            short8 k1 = *(const short8*)(&Klh[(16 + c) * 264 + (kb * 4 + q) * 8]);
            s0f = __builtin_amdgcn_mfma_f32_16x16x32_f16(qf[kb], k0, s0f, 0, 0, 0);
            s1f = __builtin_amdgcn_mfma_f32_16x16x32_f16(qf[kb], k1, s1f, 0, 0, 0);
        }

        // online softmax per C-row (row = q*4+r)
        float alpha[4];
        #pragma unroll
        for (int r = 0; r < 4; ++r) {
            float mt_ = row16_max(fmaxf(s0f[r], s1f[r]));
            float mn = fmaxf(mrow[r], mt_);
            alpha[r] = exp2f((mrow[r] - mn) * LOG2E);
            float p0 = exp2f((s0f[r] - mn) * LOG2E);
            float p1 = exp2f((s1f[r] - mn) * LOG2E);
            s0f[r] = p0; s1f[r] = p1;
            lrow[r] = lrow[r] * alpha[r] + row16_sum(p0 + p1);
            mrow[r] = mn;
        }

        // P -> per-wave LDS (C-layout -> A-layout)
        #pragma unroll
        for (int r = 0; r < 4; ++r) {
            Pw[(q * 4 + r) * 40 + c] = f2h(s0f[r]);
            Pw[(q * 4 + r) * 40 + 16 + c] = f2h(s1f[r]);
        }
        __syncthreads();  // (B) fences Kl reads (scores) before next-iter staging

        #pragma unroll
        for (int ef = 0; ef < 16; ++ef)
            #pragma unroll
            for (int r = 0; r < 4; ++r)
                oacc[ef][r] *= alpha[r];

        short8 pf = *(const short8*)(&Pw[c * 40 + q * 8]);
        #pragma unroll
        for (int ef = 0; ef < 16; ++ef)
            oacc[ef] = __builtin_amdgcn_mfma_f32_16x16x32_f16(pf, vf[ef], oacc[ef], 0, 0, 0);
    }

    // ---- flash merge of the two kv halves (wave w <-> w^1) ----
    if (c == 0) {
        #pragma unroll
        for (int r = 0; r < 4; ++r) {
            ML[w * 32 + (q * 4 + r) * 2 + 0] = mrow[r];
            ML[w * 32 + (q * 4 + r) * 2 + 1] = lrow[r];
        }
    }
    __syncthreads();  // (C)
    const int pw = w ^ 1;
    float bSelf[4], lnew[4];
    #pragma unroll
    for (int r = 0; r < 4; ++r) {
        float mp = ML[pw * 32 + (q * 4 + r) * 2 + 0];
        float lp = ML[pw * 32 + (q * 4 + r) * 2 + 1];
        float Mx = fmaxf(mrow[r], mp);
        bSelf[r] = exp2f((mrow[r] - Mx) * LOG2E);
        lnew[r] = lrow[r] * bSelf[r] + lp * exp2f((mp - Mx) * LOG2E);
    }
    float* OX = (float*)smem;
    if (hf == 1) {
        #pragma unroll
        for (int ef = 0; ef < 16; ++ef)
            #pragma unroll
            for (int r = 0; r < 4; ++r)
                OX[rg * 4096 + (q * 4 + r) * 256 + ef * 16 + c] = oacc[ef][r] * bSelf[r];
    }
    __syncthreads();  // (D) partner partials visible
    if (hf == 0) {
        #pragma unroll
        for (int ef = 0; ef < 16; ++ef)
            #pragma unroll
            for (int r = 0; r < 4; ++r)
                oacc[ef][r] = (oacc[ef][r] * bSelf[r] +
                               OX[rg * 4096 + (q * 4 + r) * 256 + ef * 16 + c]) / lnew[r];
    }
    __syncthreads();  // (E) all OX reads done before OA overwrite

    // ---- epilogue (hf0 waves): out = O' * Wov^T + bo ----
    if (hf == 0) {
        #pragma unroll
        for (int ef = 0; ef < 16; ++ef)
            #pragma unroll
            for (int r = 0; r < 4; ++r)
                smem[rg * 4224 + (q * 4 + r) * 264 + ef * 16 + c] = f2h(oacc[ef][r]);
        short8 of[8];
        #pragma unroll
        for (int kb = 0; kb < 8; ++kb)
            of[kb] = *(const short8*)(&smem[rg * 4224 + c * 264 + kb * 32 + q * 8]);

        floatx4 acc2[16];
        #pragma unroll
        for (int f = 0; f < 16; ++f) acc2[f] = (floatx4){0.f, 0.f, 0.f, 0.f};
        #pragma unroll
        for (int kb = 0; kb < 8; ++kb)
            #pragma unroll
            for (int f = 0; f < 16; ++f) {
                short8 wof = *(const short8*)(Wov + (f * 16 + c) * 256 + kb * 32 + q * 8);
                acc2[f] = __builtin_amdgcn_mfma_f32_16x16x32_f16(of[kb], wof, acc2[f], 0, 0, 0);
            }
        #pragma unroll
        for (int f = 0; f < 16; ++f) {
            float bv = bo[f * 16 + c];
            #pragma unroll
            for (int r = 0; r < 4; ++r)
                out[(long)(wrow + q * 4 + r) * 256 + f * 16 + c] = acc2[f][r] + bv;
        }
    }
}

extern "C" void kernel_launch(void* const* d_in, const int* in_sizes, int n_in,
                              void* d_out, int out_size, void* d_ws, size_t ws_size,
                              hipStream_t stream) {
    const float* q_in = (const float*)d_in[0];
    const float* k_in = (const float*)d_in[1];
    const float* v_in = (const float*)d_in[2];
    const float* Wq   = (const float*)d_in[3];
    const float* Wk   = (const float*)d_in[4];
    const float* Wv   = (const float*)d_in[5];
    const float* Wo   = (const float*)d_in[6];
    const float* bo   = (const float*)d_in[7];
    float* out = (float*)d_out;
    short* ws  = (short*)d_ws;

    short* Wmt = ws;                       // [256][256] fp16
    short* Wov = ws + 65536;               // [256][256] fp16
    short* Kh  = ws + 131072;              // [4][4096][256] fp16
    short* Vt  = ws + 131072 + 4194304;    // [4][256][4096] fp16  (total ~16.25 MB)

    pre_kernel<<<5632, 256, 0, stream>>>(Wq, Wk, Wv, Wo, k_in, v_in, Wmt, Wov, Kh, Vt);
    attn_kernel<<<512, 256, 0, stream>>>(q_in, Kh, Vt, Wmt, Wov, bo, out);
}

// Round 7
// 445.374 us; speedup vs baseline: 1.0959x; 1.0959x over previous
//
#include <hip/hip_runtime.h>
#include <hip/hip_fp16.h>
#include <math.h>

// SelfAttentionModel B=4,S=4096,H=1,E=256. fp32 in/out (harness ABI), fp16 compute.
// Factored: scores = Xq*(Wq^T Wk/16)*Xk^T ; out = (P*Xv)*(Wo Wv)^T + bo.
// ws: Wmt(128KB) + Wov(128KB) + Kh fp16 [B][S][E] (8MB) + Vt fp16 [B][E][S] (8MB).
// attn: grid 256, block 256 = 4 waves = 2 row-groups(32 rows) x 2 kv-halves(2048).
// Barrier-free K-loop: K/V B-frags direct from global (L2-hot), Q' LDS-resident,
// P round-trip in wave-private LDS, DPP softmax reductions, rescale-skip ballot.

typedef __attribute__((ext_vector_type(8))) short short8;   // 8 fp16 = MFMA A/B frag
typedef __attribute__((ext_vector_type(4))) float floatx4;  // MFMA C/D frag
typedef __attribute__((ext_vector_type(4))) float float4v;

#define LOG2E 1.4426950408889634f

__device__ __forceinline__ short f2h(float f) {
    union { __half h; short s; } u; u.h = __float2half(f); return u.s;
}

// DPP cross-lane on the VALU pipe (~4cyc vs ~120cyc ds-based __shfl).
template <int CTRL>
__device__ __forceinline__ float dpp_mov(float x) {
    return __builtin_bit_cast(float,
        __builtin_amdgcn_update_dpp(0, __builtin_bit_cast(int, x), CTRL, 0xF, 0xF, true));
}
// All-lane reduction within each 16-lane row: quad butterfly + ror4 + ror8.
__device__ __forceinline__ float row16_max(float v) {
    v = fmaxf(v, dpp_mov<0xB1>(v));    // quad_perm [1,0,3,2]  (xor1)
    v = fmaxf(v, dpp_mov<0x4E>(v));    // quad_perm [2,3,0,1]  (xor2)
    v = fmaxf(v, dpp_mov<0x124>(v));   // row_ror:4
    v = fmaxf(v, dpp_mov<0x128>(v));   // row_ror:8
    return v;
}
__device__ __forceinline__ float row16_sum(float v) {
    v += dpp_mov<0xB1>(v);
    v += dpp_mov<0x4E>(v);
    v += dpp_mov<0x124>(v);
    v += dpp_mov<0x128>(v);
    return v;
}

// ---------------------------------------------------------------------------
// Fused pre-pass (identical to R6; verified):
//  blk [0,256):    Wmt[a][b] = sum_f Wk[f][a]*Wq[f][b] / 16     (M^T)
//  blk [256,512):  Wov[f][e] = sum_j Wo[f][j]*Wv[j][e]
//  blk [512,4608): Kh = fp16(Xk)
//  blk [4608,5632): Vt = fp16(Xv) transposed to [B][E][S]
// ---------------------------------------------------------------------------
__global__ __launch_bounds__(256) void pre_kernel(
    const float* __restrict__ Wq, const float* __restrict__ Wk,
    const float* __restrict__ Wv, const float* __restrict__ Wo,
    const float* __restrict__ Xk, const float* __restrict__ Xv,
    short* __restrict__ Wmt, short* __restrict__ Wov,
    short* __restrict__ Kh, short* __restrict__ Vt)
{
    __shared__ short T[64 * 72];
    const int tid = threadIdx.x;
    const int blk = blockIdx.x;
    if (blk < 512) {
        float acc = 0.f;
        if (blk < 256) {
            const int a = blk;
            #pragma unroll 4
            for (int f = 0; f < 256; ++f)
                acc += Wk[f * 256 + a] * Wq[f * 256 + tid];
            Wmt[a * 256 + tid] = f2h(acc * 0.0625f);
        } else {
            const int f = blk - 256;
            #pragma unroll 4
            for (int j = 0; j < 256; ++j)
                acc += Wo[f * 256 + j] * Wv[j * 256 + tid];
            Wov[f * 256 + tid] = f2h(acc);
        }
    } else if (blk < 4608) {
        const long i = ((long)(blk - 512) * 256 + tid) * 4;
        float4v v = *(const float4v*)(Xk + i);
        union { short4 s4; short s[4]; } h;
        h.s[0] = f2h(v[0]); h.s[1] = f2h(v[1]); h.s[2] = f2h(v[2]); h.s[3] = f2h(v[3]);
        *(short4*)(Kh + i) = h.s4;
    } else {
        const int vb = blk - 4608;
        const int te = vb & 3, ts = (vb >> 2) & 63, b = vb >> 8;
        const int s0 = ts * 64, e0 = te * 64;
        #pragma unroll
        for (int i = 0; i < 4; ++i) {
            int idx = tid + i * 256;
            int sl = idx >> 4, f4 = idx & 15;
            float4v v = *(const float4v*)(Xv + ((long)(b * 4096 + s0 + sl) * 256 + e0 + f4 * 4));
            #pragma unroll
            for (int j = 0; j < 4; ++j)
                T[(f4 * 4 + j) * 72 + sl] = f2h(v[j]);
        }
        __syncthreads();
        #pragma unroll
        for (int i = 0; i < 2; ++i) {
            int idx = tid + i * 256;
            int el = idx >> 3, s8 = idx & 7;
            *(short8*)(Vt + ((long)(b * 256 + e0 + el) * 4096 + s0 + s8 * 8)) =
                *(const short8*)(&T[el * 72 + s8 * 8]);
        }
    }
}

// ---------------------------------------------------------------------------
// attn. LDS layout (shorts, phase-overlapped):
//  loop:    QA [2][32][264] at 0/8448 (Q' A-layout, persistent);
//           Pw per-wave [32][72] at 16896 + w*2304; ML floats at 26112.
//  merge:   OX fp32 [2][32][128] at 0 (QA/Pw dead); ML persists.
//  epilogue:OA = QA region (after barrier).
// ---------------------------------------------------------------------------
__global__ __launch_bounds__(256, 2) void attn_kernel(
    const float* __restrict__ Xq, const short* __restrict__ Kh,
    const short* __restrict__ Vt, const short* __restrict__ Wmt,
    const short* __restrict__ Wov, const float* __restrict__ bo,
    float* __restrict__ out)
{
    __shared__ short smem[26624];   // 53248 B
    const int tid = threadIdx.x;
    const int w = tid >> 6, lane = tid & 63, c = lane & 15, q = lane >> 4;
    const int rg = w >> 1, hf = w & 1;
    const int x = blockIdx.x;
    const int b = (x & 7) >> 1;                    // batch per XCD pair
    const int qt = ((x >> 3) << 1) | (x & 1);      // [0,64)
    const int wrow = b * 4096 + qt * 64 + rg * 32; // this wave's 32 q-rows

    short* QA = smem + rg * 8448;                  // [32][264]
    short* Pw = smem + 16896 + w * 2304;           // [32][72]
    float* ML = (float*)(smem + 26112);            // [4][2][16][2]

    // ---- prologue (hf==0): Q' = Xq * Wmt^T for 32 rows -> QA (A-layout) ----
    if (hf == 0) {
        #pragma unroll
        for (int mi = 0; mi < 2; ++mi) {
            short8 xa[8];
            const float* xq = Xq + (long)(wrow + mi * 16 + c) * 256;
            #pragma unroll
            for (int kb = 0; kb < 8; ++kb) {
                const float* p = xq + kb * 32 + q * 8;
                float4v lo = *(const float4v*)p, hi = *(const float4v*)(p + 4);
                short8 t;
                t[0] = f2h(lo[0]); t[1] = f2h(lo[1]); t[2] = f2h(lo[2]); t[3] = f2h(lo[3]);
                t[4] = f2h(hi[0]); t[5] = f2h(hi[1]); t[6] = f2h(hi[2]); t[7] = f2h(hi[3]);
                xa[kb] = t;
            }
            floatx4 qa[16];
            #pragma unroll
            for (int f = 0; f < 16; ++f) qa[f] = (floatx4){0.f, 0.f, 0.f, 0.f};
            #pragma unroll
            for (int kb = 0; kb < 8; ++kb)
                #pragma unroll
                for (int f = 0; f < 16; ++f) {
                    short8 wf = *(const short8*)(Wmt + (f * 16 + c) * 256 + kb * 32 + q * 8);
                    qa[f] = __builtin_amdgcn_mfma_f32_16x16x32_f16(xa[kb], wf, qa[f], 0, 0, 0);
                }
            #pragma unroll
            for (int f = 0; f < 16; ++f)
                #pragma unroll
                for (int r = 0; r < 4; ++r)
                    QA[(mi * 16 + q * 4 + r) * 264 + f * 16 + c] = f2h(qa[f][r]);
        }
    }
    __syncthreads();

    floatx4 oacc[2][16];
    #pragma unroll
    for (int mi = 0; mi < 2; ++mi)
        #pragma unroll
        for (int ef = 0; ef < 16; ++ef) oacc[mi][ef] = (floatx4){0.f, 0.f, 0.f, 0.f};
    float mrow[2][4], lrow[2][4];
    #pragma unroll
    for (int mi = 0; mi < 2; ++mi)
        #pragma unroll
        for (int r = 0; r < 4; ++r) { mrow[mi][r] = -1e30f; lrow[mi][r] = 0.f; }

    // per-lane global base pointers (B-frag gather, 16x64B coalesced per instr)
    const short* kp = Kh + ((long)(b * 4096 + hf * 2048 + c)) * 256 + q * 8;
    const short* vp = Vt + ((long)b * 256 + c) * 4096 + hf * 2048 + q * 8;

    for (int t = 0; t < 32; ++t) {   // 32 iters x 64 keys = 2048 (own half)
        const short* kt = kp + (long)t * 64 * 256;

        // ---- scores: s[mi][nf] = Q'(32 rows) x K_tile(64 keys)^T ----
        floatx4 s[2][4];
        #pragma unroll
        for (int mi = 0; mi < 2; ++mi)
            #pragma unroll
            for (int nf = 0; nf < 4; ++nf) s[mi][nf] = (floatx4){0.f, 0.f, 0.f, 0.f};
        short8 kf[4], kfn[4];
        #pragma unroll
        for (int nf = 0; nf < 4; ++nf) kfn[nf] = *(const short8*)(kt + nf * 16 * 256);
        #pragma unroll
        for (int kb = 0; kb < 8; ++kb) {
            #pragma unroll
            for (int nf = 0; nf < 4; ++nf) kf[nf] = kfn[nf];
            if (kb < 7)
                #pragma unroll
                for (int nf = 0; nf < 4; ++nf)
                    kfn[nf] = *(const short8*)(kt + nf * 16 * 256 + (kb + 1) * 32);
            #pragma unroll
            for (int mi = 0; mi < 2; ++mi) {
                short8 qf = *(const short8*)(&QA[(mi * 16 + c) * 264 + kb * 32 + q * 8]);
                #pragma unroll
                for (int nf = 0; nf < 4; ++nf)
                    s[mi][nf] = __builtin_amdgcn_mfma_f32_16x16x32_f16(qf, kf[nf], s[mi][nf], 0, 0, 0);
            }
        }

        // early-issue V frags for ef=0 (hide L2 latency behind softmax)
        const short* vt_ = vp + t * 64;
        short8 vfn[2];
        vfn[0] = *(const short8*)(vt_);
        vfn[1] = *(const short8*)(vt_ + 32);

        // ---- online softmax per row (DPP reductions, rows = mi*16 + q*4 + r) ----
        float alpha[2][4];
        bool need = false;
        #pragma unroll
        for (int mi = 0; mi < 2; ++mi)
            #pragma unroll
            for (int r = 0; r < 4; ++r) {
                float mx = fmaxf(fmaxf(s[mi][0][r], s[mi][1][r]), fmaxf(s[mi][2][r], s[mi][3][r]));
                float mt_ = row16_max(mx);
                float mn = fmaxf(mrow[mi][r], mt_);
                float a = exp2f((mrow[mi][r] - mn) * LOG2E);
                alpha[mi][r] = a;
                float p0 = exp2f((s[mi][0][r] - mn) * LOG2E);
                float p1 = exp2f((s[mi][1][r] - mn) * LOG2E);
                float p2 = exp2f((s[mi][2][r] - mn) * LOG2E);
                float p3 = exp2f((s[mi][3][r] - mn) * LOG2E);
                s[mi][0][r] = p0; s[mi][1][r] = p1; s[mi][2][r] = p2; s[mi][3][r] = p3;
                lrow[mi][r] = lrow[mi][r] * a + row16_sum(p0 + p1 + p2 + p3);
                mrow[mi][r] = mn;
                need |= (a < 1.0f);
            }

        // P -> wave-private LDS (C-layout -> A-layout; lgkmcnt orders, no barrier)
        #pragma unroll
        for (int mi = 0; mi < 2; ++mi)
            #pragma unroll
            for (int r = 0; r < 4; ++r)
                #pragma unroll
                for (int nf = 0; nf < 4; ++nf)
                    Pw[(mi * 16 + q * 4 + r) * 72 + nf * 16 + c] = f2h(s[mi][nf][r]);

        // rescale O only when some alpha < 1 (wave-uniform ballot)
        if (__ballot(need)) {
            #pragma unroll
            for (int mi = 0; mi < 2; ++mi)
                #pragma unroll
                for (int ef = 0; ef < 16; ++ef)
                    #pragma unroll
                    for (int r = 0; r < 4; ++r)
                        oacc[mi][ef][r] *= alpha[mi][r];
        }

        short8 pf[2][2];
        #pragma unroll
        for (int mi = 0; mi < 2; ++mi)
            #pragma unroll
            for (int kb = 0; kb < 2; ++kb)
                pf[mi][kb] = *(const short8*)(&Pw[(mi * 16 + c) * 72 + kb * 32 + q * 8]);

        // ---- PV: O += P x V^T (B-frags direct from global, one-ahead stage) ----
        #pragma unroll
        for (int ef = 0; ef < 16; ++ef) {
            short8 vf0 = vfn[0], vf1 = vfn[1];
            if (ef < 15) {
                vfn[0] = *(const short8*)(vt_ + (long)(ef + 1) * 16 * 4096);
                vfn[1] = *(const short8*)(vt_ + (long)(ef + 1) * 16 * 4096 + 32);
            }
            #pragma unroll
            for (int mi = 0; mi < 2; ++mi) {
                oacc[mi][ef] = __builtin_amdgcn_mfma_f32_16x16x32_f16(pf[mi][0], vf0, oacc[mi][ef], 0, 0, 0);
                oacc[mi][ef] = __builtin_amdgcn_mfma_f32_16x16x32_f16(pf[mi][1], vf1, oacc[mi][ef], 0, 0, 0);
            }
        }
    }

    // ---- exchange m,l and flash-merge the two kv halves (wave w <-> w^1) ----
    if (c == 0) {
        #pragma unroll
        for (int mi = 0; mi < 2; ++mi)
            #pragma unroll
            for (int r = 0; r < 4; ++r) {
                ML[((w * 2 + mi) * 16 + q * 4 + r) * 2 + 0] = mrow[mi][r];
                ML[((w * 2 + mi) * 16 + q * 4 + r) * 2 + 1] = lrow[mi][r];
            }
    }
    __syncthreads();
    const int pw = w ^ 1;
    float bS[2][4], lnew[2][4];
    #pragma unroll
    for (int mi = 0; mi < 2; ++mi)
        #pragma unroll
        for (int r = 0; r < 4; ++r) {
            float mp = ML[((pw * 2 + mi) * 16 + q * 4 + r) * 2 + 0];
            float lp = ML[((pw * 2 + mi) * 16 + q * 4 + r) * 2 + 1];
            float Mx = fmaxf(mrow[mi][r], mp);
            bS[mi][r] = exp2f((mrow[mi][r] - Mx) * LOG2E);
            lnew[mi][r] = lrow[mi][r] * bS[mi][r] + lp * exp2f((mp - Mx) * LOG2E);
        }
    float* OX = (float*)smem;   // [2][32][128] per ef-half
    #pragma unroll
    for (int half = 0; half < 2; ++half) {
        if (hf == 1) {
            #pragma unroll
            for (int mi = 0; mi < 2; ++mi)
                #pragma unroll
                for (int e8 = 0; e8 < 8; ++e8)
                    #pragma unroll
                    for (int r = 0; r < 4; ++r)
                        OX[rg * 4096 + (mi * 16 + q * 4 + r) * 128 + e8 * 16 + c] =
                            oacc[mi][half * 8 + e8][r] * bS[mi][r];
        }
        __syncthreads();
        if (hf == 0) {
            #pragma unroll
            for (int mi = 0; mi < 2; ++mi)
                #pragma unroll
                for (int e8 = 0; e8 < 8; ++e8)
                    #pragma unroll
                    for (int r = 0; r < 4; ++r)
                        oacc[mi][half * 8 + e8][r] =
                            (oacc[mi][half * 8 + e8][r] * bS[mi][r] +
                             OX[rg * 4096 + (mi * 16 + q * 4 + r) * 128 + e8 * 16 + c]) / lnew[mi][r];
        }
        __syncthreads();
    }

    // ---- epilogue (hf==0): out = O' * Wov^T + bo ----
    if (hf == 0) {
        #pragma unroll
        for (int mi = 0; mi < 2; ++mi)
            #pragma unroll
            for (int ef = 0; ef < 16; ++ef)
                #pragma unroll
                for (int r = 0; r < 4; ++r)
                    QA[(mi * 16 + q * 4 + r) * 264 + ef * 16 + c] = f2h(oacc[mi][ef][r]);
        #pragma unroll
        for (int mi = 0; mi < 2; ++mi) {
            floatx4 a2[16];
            #pragma unroll
            for (int f = 0; f < 16; ++f) a2[f] = (floatx4){0.f, 0.f, 0.f, 0.f};
            #pragma unroll
            for (int kb = 0; kb < 8; ++kb) {
                short8 of = *(const short8*)(&QA[(mi * 16 + c) * 264 + kb * 32 + q * 8]);
                #pragma unroll
                for (int f = 0; f < 16; ++f) {
                    short8 wof = *(const short8*)(Wov + (f * 16 + c) * 256 + kb * 32 + q * 8);
                    a2[f] = __builtin_amdgcn_mfma_f32_16x16x32_f16(of, wof, a2[f], 0, 0, 0);
                }
            }
            #pragma unroll
            for (int f = 0; f < 16; ++f) {
                float bv = bo[f * 16 + c];
                #pragma unroll
                for (int r = 0; r < 4; ++r)
                    out[(long)(wrow + mi * 16 + q * 4 + r) * 256 + f * 16 + c] = a2[f][r] + bv;
            }
        }
    }
}

extern "C" void kernel_launch(void* const* d_in, const int* in_sizes, int n_in,
                              void* d_out, int out_size, void* d_ws, size_t ws_size,
                              hipStream_t stream) {
    const float* q_in = (const float*)d_in[0];
    const float* k_in = (const float*)d_in[1];
    const float* v_in = (const float*)d_in[2];
    const float* Wq   = (const float*)d_in[3];
    const float* Wk   = (const float*)d_in[4];
    const float* Wv   = (const float*)d_in[5];
    const float* Wo   = (const float*)d_in[6];
    const float* bo   = (const float*)d_in[7];
    float* out = (float*)d_out;
    short* ws  = (short*)d_ws;

    short* Wmt = ws;                       // [256][256] fp16
    short* Wov = ws + 65536;               // [256][256] fp16
    short* Kh  = ws + 131072;              // [4][4096][256] fp16
    short* Vt  = ws + 131072 + 4194304;    // [4][256][4096] fp16

    pre_kernel<<<5632, 256, 0, stream>>>(Wq, Wk, Wv, Wo, k_in, v_in, Wmt, Wov, Kh, Vt);
    attn_kernel<<<256, 256, 0, stream>>>(q_in, Kh, Vt, Wmt, Wov, bo, out);
}